// Round 2
// baseline (2562.045 us; speedup 1.0000x reference)
//
#include <hip/hip_runtime.h>
#include <cmath>

// ---- problem constants ----
#define NB 32          // batch
#define HH 56
#define WWD 56
#define CC 256
#define WSZ 7
#define NHD 8          // heads
#define HDIM 32        // head dim
#define KCHN 16        // channel top-k
#define KSP 28         // spatial top-k
#define NTOK 49        // tokens per window
#define NWIN 2048      // Bw
#define NBH 16384      // Bw*NH
#define LL 3136        // H*W
#define MTOK 100352    // B*L
#define MLPH 1024
#define SCALE_Q 0.17677669529663689f  // 32^-0.5

__device__ __forceinline__ float gelu_f(float x) {
    return 0.5f * x * (1.0f + erff(x * 0.7071067811865475f));
}

// ---------------- LN row stats (mean, rsqrt(var+eps)) ----------------
__global__ __launch_bounds__(64) void ln_stats_k(const float* __restrict__ x,
                                                 float* __restrict__ mu,
                                                 float* __restrict__ rs) {
    int row = blockIdx.x;
    int lane = threadIdx.x;
    float4 v = reinterpret_cast<const float4*>(x + (size_t)row * CC)[lane];
    float s = v.x + v.y + v.z + v.w;
    float s2 = v.x * v.x + v.y * v.y + v.z * v.z + v.w * v.w;
#pragma unroll
    for (int off = 32; off > 0; off >>= 1) {
        s += __shfl_down(s, off);
        s2 += __shfl_down(s2, off);
    }
    if (lane == 0) {
        float m = s * (1.0f / CC);
        float var = s2 * (1.0f / CC) - m * m;
        mu[row] = m;
        rs[row] = rsqrtf(var + 1e-5f);
    }
}

// ---------------- generic tiled fp32 GEMM with fused A-ops / epilogues ----------------
// AM: 0 plain A  | 1 LN1+window-partition from x | 2 channel-gather from q (K=128)
//     3 spatial-gather from q (K=256)            | 4 LN2 from x2
// EM: 0 +bias    | 1 +bias,gelu | 2 +bias, window-reverse, +resid | 3 +bias, +resid in-place
struct GP {
    const float* A;
    const float* W;
    const float* bias;
    float* C;
    int M, N, K;
    const float* x;
    const float* mu;
    const float* rs;
    const float* g;
    const float* be;
    const int* idx;
    const float* resid;
    int row0;
};

template <int AM, int EM>
__global__ __launch_bounds__(256) void gemm_k(GP p) {
    constexpr int BM = 64, BN = 64, BK = 16;
    __shared__ float As[BK][BM + 4];
    __shared__ float Bs[BK][BN + 4];
    const int bm = blockIdx.x * BM;
    const int bn = blockIdx.y * BN;
    const int tid = threadIdx.x;
    const int tx = tid & 15;
    const int ty = tid >> 4;
    const int rowA = tid >> 2;
    const int ka4 = (tid & 3) << 2;
    const int rowB = tid >> 4;
    const int nb4 = (tid & 15) << 2;
    float acc[4][4] = {};

    for (int k0 = 0; k0 < p.K; k0 += BK) {
        {  // A tile: 64 rows x 16 k
            const int r = bm + rowA;
            const int kk = k0 + ka4;
            float4 av;
            if constexpr (AM == 0) {
                av = *reinterpret_cast<const float4*>(p.A + (size_t)r * p.K + kk);
            } else if constexpr (AM == 1) {
                int bwi = r / NTOK, n = r - bwi * NTOK;
                int b = bwi >> 6, rem = bwi & 63;
                int hw = rem >> 3, ww = rem & 7;
                int i = n / WSZ, j = n - i * WSZ;
                size_t grow = (size_t)b * LL + (size_t)(hw * WSZ + i) * WWD + (ww * WSZ + j);
                float m = p.mu[grow], rsg = p.rs[grow];
                float4 xv = *reinterpret_cast<const float4*>(p.x + grow * CC + kk);
                float4 gv = *reinterpret_cast<const float4*>(p.g + kk);
                float4 bv = *reinterpret_cast<const float4*>(p.be + kk);
                av.x = (xv.x - m) * rsg * gv.x + bv.x;
                av.y = (xv.y - m) * rsg * gv.y + bv.y;
                av.z = (xv.z - m) * rsg * gv.z + bv.z;
                av.w = (xv.w - m) * rsg * gv.w + bv.w;
            } else if constexpr (AM == 2) {
                int bwi = r / NTOK;
                int hp = kk >> 4, c = kk & 15;
                const int* ci = p.idx + ((size_t)(bwi * NHD + hp)) * KCHN + c;
                const float* qrow = p.x + (size_t)r * CC + hp * HDIM;
                av.x = qrow[ci[0]];
                av.y = qrow[ci[1]];
                av.z = qrow[ci[2]];
                av.w = qrow[ci[3]];
            } else if constexpr (AM == 3) {
                int bwi = r / KSP, s = r - bwi * KSP;
                int hp = kk >> 5;
                int tok = p.idx[((size_t)(bwi * NHD + hp)) * KSP + s];
                av = *reinterpret_cast<const float4*>(p.x + ((size_t)(bwi * NTOK + tok)) * CC + kk);
            } else {  // AM == 4
                float m = p.mu[r], rsg = p.rs[r];
                float4 xv = *reinterpret_cast<const float4*>(p.x + (size_t)r * CC + kk);
                float4 gv = *reinterpret_cast<const float4*>(p.g + kk);
                float4 bv = *reinterpret_cast<const float4*>(p.be + kk);
                av.x = (xv.x - m) * rsg * gv.x + bv.x;
                av.y = (xv.y - m) * rsg * gv.y + bv.y;
                av.z = (xv.z - m) * rsg * gv.z + bv.z;
                av.w = (xv.w - m) * rsg * gv.w + bv.w;
            }
            As[ka4 + 0][rowA] = av.x;
            As[ka4 + 1][rowA] = av.y;
            As[ka4 + 2][rowA] = av.z;
            As[ka4 + 3][rowA] = av.w;
        }
        {  // B tile: 16 k x 64 n
            float4 bv = *reinterpret_cast<const float4*>(p.W + (size_t)(k0 + rowB) * p.N + bn + nb4);
            Bs[rowB][nb4 + 0] = bv.x;
            Bs[rowB][nb4 + 1] = bv.y;
            Bs[rowB][nb4 + 2] = bv.z;
            Bs[rowB][nb4 + 3] = bv.w;
        }
        __syncthreads();
#pragma unroll
        for (int kk = 0; kk < BK; ++kk) {
            float a[4], b[4];
#pragma unroll
            for (int u = 0; u < 4; ++u) {
                a[u] = As[kk][ty * 4 + u];
                b[u] = Bs[kk][tx * 4 + u];
            }
#pragma unroll
            for (int i = 0; i < 4; ++i)
#pragma unroll
                for (int j = 0; j < 4; ++j) acc[i][j] = fmaf(a[i], b[j], acc[i][j]);
        }
        __syncthreads();
    }

#pragma unroll
    for (int i = 0; i < 4; ++i) {
        const int r = bm + ty * 4 + i;
#pragma unroll
        for (int j = 0; j < 4; ++j) {
            const int n = bn + tx * 4 + j;
            float v = acc[i][j] + p.bias[n];
            if constexpr (EM == 1) v = gelu_f(v);
            if constexpr (EM == 2) {
                int bwi = r / NTOK, nn = r - bwi * NTOK;
                int b = bwi >> 6, rem = bwi & 63;
                int hw = rem >> 3, wwp = rem & 7;
                int ii = nn / WSZ, jj = nn - ii * WSZ;
                size_t oidx = ((size_t)b * LL + (size_t)(hw * WSZ + ii) * WWD + (wwp * WSZ + jj)) * CC + n;
                p.C[oidx] = v + p.resid[oidx];
            } else if constexpr (EM == 3) {
                size_t gr = (size_t)(r + p.row0);
                p.C[gr * p.N + n] = v + p.resid[gr * CC + n];  // in-place: 1 thread per address
            } else {
                p.C[(size_t)r * p.N + n] = v;
            }
        }
    }
}

// ---------------- channel + spatial top-k (one wave per head-window) ----------------
__global__ __launch_bounds__(64) void topk_k(const float* __restrict__ q,
                                             const float* __restrict__ wch,
                                             const float* __restrict__ bch,
                                             int* __restrict__ cidx,
                                             int* __restrict__ sidx) {
    int bnh = blockIdx.x;          // Bw*NH
    int bwi = bnh >> 3, h = bnh & 7;
    int lane = threadIdx.x;
    __shared__ float tile[NTOK][HDIM + 1];
    __shared__ float feat[2 * HDIM];
    __shared__ float score[HDIM];
    __shared__ float rowm[NTOK];
    const float* qbase = q + ((size_t)bwi * NTOK) * CC + h * HDIM;
    for (int idx = lane; idx < NTOK * HDIM; idx += 64) {
        int n = idx >> 5, d = idx & 31;
        tile[n][d] = qbase[(size_t)n * CC + d];
    }
    __syncthreads();
    if (lane < HDIM) {
        float s = 0.f, mx = -INFINITY;
        for (int n = 0; n < NTOK; ++n) {
            float v = tile[n][lane];
            s += v;
            mx = fmaxf(mx, v);
        }
        feat[lane] = s * (1.0f / NTOK);
        feat[HDIM + lane] = mx;
    }
    if (lane < NTOK) {
        float s = 0.f;
        for (int d = 0; d < HDIM; ++d) s += tile[lane][d];
        rowm[lane] = s;   // mean-over-HD scaled by HD: same ordering
    }
    __syncthreads();
    if (lane < HDIM) {
        float s = bch[lane];
        for (int j = 0; j < 2 * HDIM; ++j) s += feat[j] * wch[j * HDIM + lane];
        score[lane] = gelu_f(s);   // softmax is monotonic: skip for top-k
    }
    __syncthreads();
    {  // channel top-16, stable tie rule (lower index first), output ascending
        bool sel = false;
        if (lane < HDIM) {
            float sv = score[lane];
            int rank = 0;
            for (int j = 0; j < HDIM; ++j) {
                float oj = score[j];
                rank += (oj > sv) || (oj == sv && j < lane);
            }
            sel = rank < KCHN;
        }
        unsigned long long m = __ballot(sel);
        if (sel) {
            int pos = __popcll(m & ((1ull << lane) - 1ull));
            cidx[(size_t)bnh * KCHN + pos] = lane;
        }
    }
    {  // spatial top-28
        bool sel = false;
        if (lane < NTOK) {
            float sv = rowm[lane];
            int rank = 0;
            for (int j = 0; j < NTOK; ++j) {
                float oj = rowm[j];
                rank += (oj > sv) || (oj == sv && j < lane);
            }
            sel = rank < KSP;
        }
        unsigned long long m = __ballot(sel);
        if (sel) {
            int pos = __popcll(m & ((1ull << lane) - 1ull));
            sidx[(size_t)bnh * KSP + pos] = lane;
        }
    }
}

// ---------------- attention (one wave per head-window, one token row per lane) ----------
// NOTE: ob may alias q. Block (bwi,h) reads q only at rows of window bwi, cols
// [h*32,h*32+32) (all gathers complete before the barrier), and writes o at exactly
// that same slice. Slices are disjoint across blocks -> in-place safe.
__global__ __launch_bounds__(64) void attn_k(const float* __restrict__ q,
                                             const float* __restrict__ kb,
                                             const float* __restrict__ vb,
                                             const int* __restrict__ cidx,
                                             const int* __restrict__ sidx,
                                             const float* __restrict__ rpb,
                                             float* __restrict__ ob) {
    int bnh = blockIdx.x;
    int bwi = bnh >> 3, h = bnh & 7;
    int lane = threadIdx.x;
    __shared__ float kh_s[NTOK][KCHN + 1];
    __shared__ float qs_s[KSP][KCHN];
    __shared__ float v_s[KSP][HDIM];
    __shared__ int sidx_s[KSP];
    __shared__ int cidx_s[KCHN];
    if (lane < KSP) sidx_s[lane] = sidx[(size_t)bnh * KSP + lane];
    if (lane < KCHN) cidx_s[lane] = cidx[(size_t)bnh * KCHN + lane];
    for (int idx = lane; idx < NTOK * KCHN; idx += 64) {
        int n = idx >> 4, c = idx & 15;
        kh_s[n][c] = kb[((size_t)bwi * NTOK + n) * (NHD * KCHN) + h * KCHN + c];
    }
    for (int idx = lane; idx < KSP * HDIM; idx += 64) {
        int s = idx >> 5, d = idx & 31;
        v_s[s][d] = vb[((size_t)bwi * KSP + s) * CC + h * HDIM + d];
    }
    __syncthreads();
    for (int idx = lane; idx < KSP * KCHN; idx += 64) {
        int s = idx >> 4, c = idx & 15;
        qs_s[s][c] = q[((size_t)bwi * NTOK + sidx_s[s]) * CC + h * HDIM + cidx_s[c]] * SCALE_Q;
    }
    __syncthreads();
    if (lane < NTOK) {
        int i1 = lane / WSZ, j1 = lane - i1 * WSZ;
        float a[KSP];
        float msum = 0.f;
#pragma unroll
        for (int s = 0; s < KSP; ++s) {
            float dot = 0.f;
#pragma unroll
            for (int c = 0; c < KCHN; ++c) dot += kh_s[lane][c] * qs_s[s][c];
            int m = sidx_s[s];
            int i2 = m / WSZ, j2 = m - i2 * WSZ;
            float bias = rpb[(size_t)((i1 - i2 + 6) * 13 + (j1 - j2 + 6)) * NHD + h];
            a[s] = dot + bias;
            msum += a[s];
        }
        float gate = 1.0f / (1.0f + expf(-msum * (1.0f / KSP)));
        float mx = -INFINITY;
#pragma unroll
        for (int s = 0; s < KSP; ++s) mx = fmaxf(mx, a[s]);
        float sum = 0.f;
#pragma unroll
        for (int s = 0; s < KSP; ++s) {
            a[s] = expf(a[s] - mx);
            sum += a[s];
        }
        float inv = gate / sum;
        float* orow = ob + ((size_t)bwi * NTOK + lane) * CC + h * HDIM;
#pragma unroll
        for (int d = 0; d < HDIM; ++d) {
            float od = 0.f;
#pragma unroll
            for (int s = 0; s < KSP; ++s) od += a[s] * v_s[s][d];
            orow[d] = od * inv;
        }
    }
}

// ---------------- driver ----------------
extern "C" void kernel_launch(void* const* d_in, const int* in_sizes, int n_in,
                              void* d_out, int out_size, void* d_ws, size_t ws_size,
                              hipStream_t stream) {
    const float* x   = (const float*)d_in[0];
    const float* n1g = (const float*)d_in[1];
    const float* n1b = (const float*)d_in[2];
    const float* wq  = (const float*)d_in[3];
    const float* bq  = (const float*)d_in[4];
    const float* wk  = (const float*)d_in[5];
    const float* bk  = (const float*)d_in[6];
    const float* wv  = (const float*)d_in[7];
    const float* bv  = (const float*)d_in[8];
    const float* wpj = (const float*)d_in[9];
    const float* bpj = (const float*)d_in[10];
    const float* wch = (const float*)d_in[11];
    const float* bch = (const float*)d_in[12];
    const float* rpb = (const float*)d_in[13];
    const float* n2g = (const float*)d_in[14];
    const float* n2b = (const float*)d_in[15];
    const float* w1  = (const float*)d_in[16];
    const float* b1  = (const float*)d_in[17];
    const float* w2  = (const float*)d_in[18];
    const float* b2  = (const float*)d_in[19];
    float* out = (float*)d_out;

    // ---- workspace layout (~207 MiB) ----
    float* ws = (float*)d_ws;
    const size_t S = (size_t)MTOK * CC;     // 25,690,112 floats
    float* qb  = ws;                        // q (Bw,N,C); attn writes o in place; later MLP h-chunk
    float* kb  = ws + S;                    // k (Bw,N,128)
    float* vb  = kb + (size_t)MTOK * 128;   // v (Bw,28,C)
    float* mu1 = vb + (size_t)NWIN * KSP * CC;
    float* rs1 = mu1 + MTOK;
    float* mu2 = rs1 + MTOK;
    float* rs2 = mu2 + MTOK;
    int* cidx  = (int*)(rs2 + MTOK);
    int* sidx  = cidx + (size_t)NBH * KCHN;
    const size_t need_bytes = (size_t)((sidx + (size_t)NBH * KSP) - (int*)d_ws) * 4;
    if (ws_size < need_bytes) return;       // avoid OOB fault; deterministic per call

    GP p;

    ln_stats_k<<<MTOK, 64, 0, stream>>>(x, mu1, rs1);

    // q = (LN1(x) windowed) @ wq + bq
    p = GP{};
    p.W = wq; p.bias = bq; p.C = qb; p.M = MTOK; p.N = CC; p.K = CC;
    p.x = x; p.mu = mu1; p.rs = rs1; p.g = n1g; p.be = n1b;
    gemm_k<1, 0><<<dim3(MTOK / 64, CC / 64), 256, 0, stream>>>(p);

    topk_k<<<NBH, 64, 0, stream>>>(qb, wch, bch, cidx, sidx);

    // k = gather_channels(q) @ wk + bk
    p = GP{};
    p.W = wk; p.bias = bk; p.C = kb; p.M = MTOK; p.N = 128; p.K = 128;
    p.x = qb; p.idx = cidx;
    gemm_k<2, 0><<<dim3(MTOK / 64, 128 / 64), 256, 0, stream>>>(p);

    // v = gather_tokens(q) @ wv + bv
    p = GP{};
    p.W = wv; p.bias = bv; p.C = vb; p.M = NWIN * KSP; p.N = CC; p.K = CC;
    p.x = qb; p.idx = sidx;
    gemm_k<3, 0><<<dim3(NWIN * KSP / 64, CC / 64), 256, 0, stream>>>(p);

    // attention: o written in place over q (disjoint per-block slices)
    attn_k<<<NBH, 64, 0, stream>>>(qb, kb, vb, cidx, sidx, rpb, qb);

    // out = x2 = window_reverse(o @ wproj + bproj) + x
    p = GP{};
    p.A = qb; p.W = wpj; p.bias = bpj; p.C = out; p.M = MTOK; p.N = CC; p.K = CC;
    p.resid = x;
    gemm_k<0, 2><<<dim3(MTOK / 64, CC / 64), 256, 0, stream>>>(p);

    ln_stats_k<<<MTOK, 64, 0, stream>>>(out, mu2, rs2);

    // MLP, chunked over rows; h-chunk (25088x1024) reuses qb region (exact fit)
    const int CHUNK = MTOK / 4;
    float* hb = qb;
    for (int c = 0; c < 4; ++c) {
        int start = c * CHUNK;
        p = GP{};
        p.W = w1; p.bias = b1; p.C = hb; p.M = CHUNK; p.N = MLPH; p.K = CC;
        p.x = out + (size_t)start * CC; p.mu = mu2 + start; p.rs = rs2 + start;
        p.g = n2g; p.be = n2b;
        gemm_k<4, 1><<<dim3(CHUNK / 64, MLPH / 64), 256, 0, stream>>>(p);

        p = GP{};
        p.A = hb; p.W = w2; p.bias = b2; p.C = out; p.M = CHUNK; p.N = CC; p.K = MLPH;
        p.resid = out; p.row0 = start;
        gemm_k<0, 3><<<dim3(CHUNK / 64, CC / 64), 256, 0, stream>>>(p);
    }
}

// Round 4
// 1166.966 us; speedup vs baseline: 2.1955x; 2.1955x over previous
//
#include <hip/hip_runtime.h>
#include <hip/hip_bf16.h>
#include <cmath>

// ---- problem constants ----
#define CC 256
#define WSZ 7
#define WWD_ 56
#define NHD 8
#define HDIM 32
#define KCHN 16
#define KSP 28
#define NTOK 49
#define NWIN 2048
#define NBH 16384
#define LL 3136
#define MTOK 100352
#define MLPH 1024
#define SCALE_Q 0.17677669529663689f

typedef float floatx4 __attribute__((ext_vector_type(4)));
typedef __bf16 bf16x8_t __attribute__((ext_vector_type(8)));

__device__ __forceinline__ float gelu_f(float x) {
    return 0.5f * x * (1.0f + erff(x * 0.7071067811865475f));
}

// ---------------- LN row stats ----------------
__global__ __launch_bounds__(64) void ln_stats_k(const float* __restrict__ x,
                                                 float* __restrict__ mu,
                                                 float* __restrict__ rs) {
    int row = blockIdx.x;
    int lane = threadIdx.x;
    float4 v = reinterpret_cast<const float4*>(x + (size_t)row * CC)[lane];
    float s = v.x + v.y + v.z + v.w;
    float s2 = v.x * v.x + v.y * v.y + v.z * v.z + v.w * v.w;
#pragma unroll
    for (int off = 32; off > 0; off >>= 1) {
        s += __shfl_down(s, off);
        s2 += __shfl_down(s2, off);
    }
    if (lane == 0) {
        float m = s * (1.0f / CC);
        float var = s2 * (1.0f / CC) - m * m;
        mu[row] = m;
        rs[row] = rsqrtf(var + 1e-5f);
    }
}

// ---------------- fp32 GEMM for the q path only (top-k selection needs fp32 q) --------
struct GP {
    const float* W;
    const float* bias;
    float* C;
    int N, K;
    const float* x;
    const float* mu;
    const float* rs;
    const float* g;
    const float* be;
};

__global__ __launch_bounds__(256) void gemm_q_k(GP p) {
    constexpr int BM = 64, BN = 64, BK = 16;
    __shared__ float As[BK][BM + 4];
    __shared__ float Bs[BK][BN + 4];
    const int bm = blockIdx.x * BM;
    const int bn = blockIdx.y * BN;
    const int tid = threadIdx.x;
    const int tx = tid & 15;
    const int ty = tid >> 4;
    const int rowA = tid >> 2;
    const int ka4 = (tid & 3) << 2;
    const int rowB = tid >> 4;
    const int nb4 = (tid & 15) << 2;
    float acc[4][4] = {};

    // LN1 + window-partition fused into the A load
    const int r = bm + rowA;
    int bwi = r / NTOK, n = r - bwi * NTOK;
    int b = bwi >> 6, rem = bwi & 63;
    int hw = rem >> 3, ww = rem & 7;
    int i0 = n / WSZ, j0 = n - i0 * WSZ;
    size_t grow = (size_t)b * LL + (size_t)(hw * WSZ + i0) * WWD_ + (ww * WSZ + j0);

    for (int k0 = 0; k0 < p.K; k0 += BK) {
        {
            const int kk = k0 + ka4;
            float m = p.mu[grow], rsg = p.rs[grow];
            float4 xv = *reinterpret_cast<const float4*>(p.x + grow * CC + kk);
            float4 gv = *reinterpret_cast<const float4*>(p.g + kk);
            float4 bv = *reinterpret_cast<const float4*>(p.be + kk);
            As[ka4 + 0][rowA] = (xv.x - m) * rsg * gv.x + bv.x;
            As[ka4 + 1][rowA] = (xv.y - m) * rsg * gv.y + bv.y;
            As[ka4 + 2][rowA] = (xv.z - m) * rsg * gv.z + bv.z;
            As[ka4 + 3][rowA] = (xv.w - m) * rsg * gv.w + bv.w;
        }
        {
            float4 bv = *reinterpret_cast<const float4*>(p.W + (size_t)(k0 + rowB) * p.N + bn + nb4);
            Bs[rowB][nb4 + 0] = bv.x;
            Bs[rowB][nb4 + 1] = bv.y;
            Bs[rowB][nb4 + 2] = bv.z;
            Bs[rowB][nb4 + 3] = bv.w;
        }
        __syncthreads();
#pragma unroll
        for (int kk = 0; kk < BK; ++kk) {
            float a[4], bb[4];
#pragma unroll
            for (int u = 0; u < 4; ++u) {
                a[u] = As[kk][ty * 4 + u];
                bb[u] = Bs[kk][tx * 4 + u];
            }
#pragma unroll
            for (int i = 0; i < 4; ++i)
#pragma unroll
                for (int j = 0; j < 4; ++j) acc[i][j] = fmaf(a[i], bb[j], acc[i][j]);
        }
        __syncthreads();
    }
#pragma unroll
    for (int i = 0; i < 4; ++i) {
        const int rr = bm + ty * 4 + i;
#pragma unroll
        for (int j = 0; j < 4; ++j) {
            const int nn = bn + tx * 4 + j;
            p.C[(size_t)rr * p.N + nn] = acc[i][j] + p.bias[nn];
        }
    }
}

// ---------------- bf16 MFMA GEMM: A (M x K bf16), B (N x K bf16, pre-transposed) -------
// EPI: 0 = +bias -> bf16 | 1 = +bias, window-reverse, +resid -> f32
//      2 = +bias, gelu -> bf16 | 3 = +bias, +resid in-place -> f32 (rows offset row0)
struct MG {
    const __hip_bfloat16* A;
    const __hip_bfloat16* B;
    const float* bias;
    int N, K;
    float* Cf;
    __hip_bfloat16* Cb;
    const float* resid;
    int row0;
};

template <int EPI>
__global__ __launch_bounds__(256) void mgemm_k(MG p) {
    __shared__ __align__(16) __hip_bfloat16 As[128 * 32];
    __shared__ __align__(16) __hip_bfloat16 Bs[128 * 32];
    const int bm = blockIdx.x * 128;
    const int bn = blockIdx.y * 128;
    const int t = threadIdx.x;
    const int lane = t & 63;
    const int w = t >> 6;
    const int wm = (w & 1) * 64;
    const int wn = (w >> 1) * 64;
    const int fr = lane & 15;
    const int fk = (lane >> 4) * 8;

    // staging: thread covers 16B chunks t and t+256; chunk c -> row c>>2, k-chunk c&3
    const int m0 = t >> 2, m1 = (t + 256) >> 2;
    const int kc = (t & 3) * 8;
    const __hip_bfloat16* a0 = p.A + (size_t)(bm + m0) * p.K + kc;
    const __hip_bfloat16* a1 = p.A + (size_t)(bm + m1) * p.K + kc;
    const __hip_bfloat16* b0 = p.B + (size_t)(bn + m0) * p.K + kc;
    const __hip_bfloat16* b1 = p.B + (size_t)(bn + m1) * p.K + kc;

    floatx4 acc[4][4] = {};

    for (int k0 = 0; k0 < p.K; k0 += 32) {
        *(uint4*)&As[m0 * 32 + kc] = *(const uint4*)(a0 + k0);
        *(uint4*)&As[m1 * 32 + kc] = *(const uint4*)(a1 + k0);
        *(uint4*)&Bs[m0 * 32 + kc] = *(const uint4*)(b0 + k0);
        *(uint4*)&Bs[m1 * 32 + kc] = *(const uint4*)(b1 + k0);
        __syncthreads();
        bf16x8_t af[4], bf[4];
#pragma unroll
        for (int i = 0; i < 4; ++i)
            af[i] = *(const bf16x8_t*)&As[(wm + i * 16 + fr) * 32 + fk];
#pragma unroll
        for (int j = 0; j < 4; ++j)
            bf[j] = *(const bf16x8_t*)&Bs[(wn + j * 16 + fr) * 32 + fk];
#pragma unroll
        for (int i = 0; i < 4; ++i)
#pragma unroll
            for (int j = 0; j < 4; ++j)
                acc[i][j] = __builtin_amdgcn_mfma_f32_16x16x32_bf16(af[i], bf[j], acc[i][j], 0, 0, 0);
        __syncthreads();
    }

    // epilogue: C/D layout col = lane&15, row = (lane>>4)*4 + reg  [m89-verified]
    float bj[4];
#pragma unroll
    for (int j = 0; j < 4; ++j) bj[j] = p.bias[bn + wn + j * 16 + fr];
#pragma unroll
    for (int i = 0; i < 4; ++i) {
#pragma unroll
        for (int r = 0; r < 4; ++r) {
            const int m = bm + wm + i * 16 + (lane >> 4) * 4 + r;
#pragma unroll
            for (int j = 0; j < 4; ++j) {
                const int n = bn + wn + j * 16 + fr;
                float v = acc[i][j][r] + bj[j];
                if constexpr (EPI == 0) {
                    p.Cb[(size_t)m * p.N + n] = __float2bfloat16(v);
                } else if constexpr (EPI == 1) {
                    int bwi = m / NTOK, nn = m - bwi * NTOK;
                    int b = bwi >> 6, rem = bwi & 63;
                    int hw = rem >> 3, wwp = rem & 7;
                    int ii = nn / WSZ, jj = nn - ii * WSZ;
                    size_t oidx = ((size_t)b * LL + (size_t)(hw * WSZ + ii) * WWD_ + (wwp * WSZ + jj)) * CC + n;
                    p.Cf[oidx] = v + p.resid[oidx];
                } else if constexpr (EPI == 2) {
                    p.Cb[(size_t)m * p.N + n] = __float2bfloat16(gelu_f(v));
                } else {
                    size_t gr = (size_t)(m + p.row0);
                    p.Cf[gr * p.N + n] = v + p.resid[gr * p.N + n];
                }
            }
        }
    }
}

// ---------------- weight transpose + bf16 convert: W (K x N f32) -> Wt (N x K bf16) ----
__global__ __launch_bounds__(256) void wt_k(const float* __restrict__ W,
                                            __hip_bfloat16* __restrict__ Wt, int K, int N) {
    int g = blockIdx.x * 256 + threadIdx.x;
    if (g >= K * N) return;
    int n = g / K, kk = g - n * K;
    Wt[g] = __float2bfloat16(W[(size_t)kk * N + n]);
}

// ---------------- top-k (channel 16/32, spatial 28/49) ----------------
__global__ __launch_bounds__(64) void topk_k(const float* __restrict__ q,
                                             const float* __restrict__ wch,
                                             const float* __restrict__ bch,
                                             short* __restrict__ cidx,
                                             short* __restrict__ sidx) {
    int bnh = blockIdx.x;
    int bwi = bnh >> 3, h = bnh & 7;
    int lane = threadIdx.x;
    __shared__ float tile[NTOK][HDIM + 1];
    __shared__ float feat[2 * HDIM];
    __shared__ float score[HDIM];
    __shared__ float rowm[NTOK];
    const float* qbase = q + ((size_t)bwi * NTOK) * CC + h * HDIM;
    for (int idx = lane; idx < NTOK * HDIM; idx += 64) {
        int n = idx >> 5, d = idx & 31;
        tile[n][d] = qbase[(size_t)n * CC + d];
    }
    __syncthreads();
    if (lane < HDIM) {
        float s = 0.f, mx = -INFINITY;
        for (int n = 0; n < NTOK; ++n) {
            float v = tile[n][lane];
            s += v;
            mx = fmaxf(mx, v);
        }
        feat[lane] = s * (1.0f / NTOK);
        feat[HDIM + lane] = mx;
    }
    if (lane < NTOK) {
        float s = 0.f;
        for (int d = 0; d < HDIM; ++d) s += tile[lane][d];
        rowm[lane] = s;
    }
    __syncthreads();
    if (lane < HDIM) {
        float s = bch[lane];
        for (int j = 0; j < 2 * HDIM; ++j) s += feat[j] * wch[j * HDIM + lane];
        score[lane] = gelu_f(s);   // softmax is monotonic: skip for top-k
    }
    __syncthreads();
    {
        bool sel = false;
        if (lane < HDIM) {
            float sv = score[lane];
            int rank = 0;
            for (int j = 0; j < HDIM; ++j) {
                float oj = score[j];
                rank += (oj > sv) || (oj == sv && j < lane);
            }
            sel = rank < KCHN;
        }
        unsigned long long m = __ballot(sel);
        if (sel) {
            int pos = __popcll(m & ((1ull << lane) - 1ull));
            cidx[(size_t)bnh * KCHN + pos] = (short)lane;
        }
    }
    {
        bool sel = false;
        if (lane < NTOK) {
            float sv = rowm[lane];
            int rank = 0;
            for (int j = 0; j < NTOK; ++j) {
                float oj = rowm[j];
                rank += (oj > sv) || (oj == sv && j < lane);
            }
            sel = rank < KSP;
        }
        unsigned long long m = __ballot(sel);
        if (sel) {
            int pos = __popcll(m & ((1ull << lane) - 1ull));
            sidx[(size_t)bnh * KSP + pos] = (short)lane;
        }
    }
}

// ---------------- gathers -> bf16 GEMM inputs ----------------
__global__ __launch_bounds__(256) void gather_ch_k(const float* __restrict__ q,
                                                   const short* __restrict__ cidx,
                                                   __hip_bfloat16* __restrict__ ak) {
    int g = blockIdx.x * 256 + threadIdx.x;   // MTOK*128 elements
    int r = g >> 7, kk = g & 127;
    int bwi = r / NTOK;
    int hp = kk >> 4, c = kk & 15;
    int ci = cidx[((size_t)(bwi * NHD + hp)) * KCHN + c];
    ak[g] = __float2bfloat16(q[(size_t)r * CC + hp * HDIM + ci]);
}

__global__ __launch_bounds__(256) void gather_sp_k(const float* __restrict__ q,
                                                   const short* __restrict__ sidx,
                                                   __hip_bfloat16* __restrict__ av) {
    int g = blockIdx.x * 256 + threadIdx.x;   // NWIN*KSP*256 elements
    int rr = g >> 8, c = g & 255;
    int bwi = rr / KSP, s = rr - bwi * KSP;
    int tok = sidx[((size_t)(bwi * NHD + (c >> 5))) * KSP + s];
    av[g] = __float2bfloat16(q[((size_t)(bwi * NTOK + tok)) * CC + c]);
}

// ---------------- attention (one wave per head-window) ----------------
__global__ __launch_bounds__(64) void attn_k(const float* __restrict__ q,
                                             const __hip_bfloat16* __restrict__ kb,
                                             const __hip_bfloat16* __restrict__ vb,
                                             const short* __restrict__ cidx,
                                             const short* __restrict__ sidx,
                                             const float* __restrict__ rpb,
                                             __hip_bfloat16* __restrict__ ob) {
    int bnh = blockIdx.x;
    int bwi = bnh >> 3, h = bnh & 7;
    int lane = threadIdx.x;
    __shared__ float kh_s[NTOK][KCHN + 1];
    __shared__ float qs_s[KSP][KCHN];
    __shared__ float v_s[KSP][HDIM];
    __shared__ int sidx_s[KSP];
    __shared__ int cidx_s[KCHN];
    if (lane < KSP) sidx_s[lane] = sidx[(size_t)bnh * KSP + lane];
    if (lane < KCHN) cidx_s[lane] = cidx[(size_t)bnh * KCHN + lane];
    for (int idx = lane; idx < NTOK * KCHN; idx += 64) {
        int n = idx >> 4, c = idx & 15;
        kh_s[n][c] = __bfloat162float(kb[((size_t)bwi * NTOK + n) * (NHD * KCHN) + h * KCHN + c]);
    }
    for (int idx = lane; idx < KSP * HDIM; idx += 64) {
        int s = idx >> 5, d = idx & 31;
        v_s[s][d] = __bfloat162float(vb[((size_t)bwi * KSP + s) * CC + h * HDIM + d]);
    }
    __syncthreads();
    for (int idx = lane; idx < KSP * KCHN; idx += 64) {
        int s = idx >> 4, c = idx & 15;
        qs_s[s][c] = q[((size_t)bwi * NTOK + sidx_s[s]) * CC + h * HDIM + cidx_s[c]] * SCALE_Q;
    }
    __syncthreads();
    if (lane < NTOK) {
        int i1 = lane / WSZ, j1 = lane - i1 * WSZ;
        float a[KSP];
        float msum = 0.f;
#pragma unroll
        for (int s = 0; s < KSP; ++s) {
            float dot = 0.f;
#pragma unroll
            for (int c = 0; c < KCHN; ++c) dot += kh_s[lane][c] * qs_s[s][c];
            int m = sidx_s[s];
            int i2 = m / WSZ, j2 = m - i2 * WSZ;
            float bias = rpb[(size_t)((i1 - i2 + 6) * 13 + (j1 - j2 + 6)) * NHD + h];
            a[s] = dot + bias;
            msum += a[s];
        }
        float gate = 1.0f / (1.0f + expf(-msum * (1.0f / KSP)));
        float mx = -INFINITY;
#pragma unroll
        for (int s = 0; s < KSP; ++s) mx = fmaxf(mx, a[s]);
        float sum = 0.f;
#pragma unroll
        for (int s = 0; s < KSP; ++s) {
            a[s] = expf(a[s] - mx);
            sum += a[s];
        }
        float inv = gate / sum;
        __hip_bfloat16* orow = ob + ((size_t)bwi * NTOK + lane) * CC + h * HDIM;
#pragma unroll
        for (int d = 0; d < HDIM; ++d) {
            float od = 0.f;
#pragma unroll
            for (int s = 0; s < KSP; ++s) od += a[s] * v_s[s][d];
            orow[d] = __float2bfloat16(od * inv);
        }
    }
}

// ---------------- LN2 fused normalize -> bf16 ----------------
__global__ __launch_bounds__(64) void ln2_k(const float* __restrict__ x2,
                                            const float* __restrict__ g,
                                            const float* __restrict__ b,
                                            __hip_bfloat16* __restrict__ a2) {
    int row = blockIdx.x;
    int lane = threadIdx.x;
    float4 v = reinterpret_cast<const float4*>(x2 + (size_t)row * CC)[lane];
    float s = v.x + v.y + v.z + v.w;
    float s2 = v.x * v.x + v.y * v.y + v.z * v.z + v.w * v.w;
#pragma unroll
    for (int off = 1; off < 64; off <<= 1) {
        s += __shfl_xor(s, off);
        s2 += __shfl_xor(s2, off);
    }
    float m = s * (1.0f / CC);
    float rsg = rsqrtf(s2 * (1.0f / CC) - m * m + 1e-5f);
    float4 gv = reinterpret_cast<const float4*>(g)[lane];
    float4 bv = reinterpret_cast<const float4*>(b)[lane];
    __hip_bfloat16* orow = a2 + (size_t)row * CC + lane * 4;
    orow[0] = __float2bfloat16((v.x - m) * rsg * gv.x + bv.x);
    orow[1] = __float2bfloat16((v.y - m) * rsg * gv.y + bv.y);
    orow[2] = __float2bfloat16((v.z - m) * rsg * gv.z + bv.z);
    orow[3] = __float2bfloat16((v.w - m) * rsg * gv.w + bv.w);
}

// ---------------- driver ----------------
extern "C" void kernel_launch(void* const* d_in, const int* in_sizes, int n_in,
                              void* d_out, int out_size, void* d_ws, size_t ws_size,
                              hipStream_t stream) {
    const float* x   = (const float*)d_in[0];
    const float* n1g = (const float*)d_in[1];
    const float* n1b = (const float*)d_in[2];
    const float* wq  = (const float*)d_in[3];
    const float* bq  = (const float*)d_in[4];
    const float* wk  = (const float*)d_in[5];
    const float* bk  = (const float*)d_in[6];
    const float* wv  = (const float*)d_in[7];
    const float* bv  = (const float*)d_in[8];
    const float* wpj = (const float*)d_in[9];
    const float* bpj = (const float*)d_in[10];
    const float* wch = (const float*)d_in[11];
    const float* bch = (const float*)d_in[12];
    const float* rpb = (const float*)d_in[13];
    const float* n2g = (const float*)d_in[14];
    const float* n2b = (const float*)d_in[15];
    const float* w1  = (const float*)d_in[16];
    const float* b1  = (const float*)d_in[17];
    const float* w2  = (const float*)d_in[18];
    const float* b2  = (const float*)d_in[19];
    float* out = (float*)d_out;

    // ---- workspace layout (216,449,024 B <= known-good 217,350,144 B) ----
    char* wsb = (char*)d_ws;
    float* qb            = (float*)wsb;                              // 102,760,448 (f32 q)
    __hip_bfloat16* g1   = (__hip_bfloat16*)(wsb + 102760448);       //  25,690,112 (a_k)
    __hip_bfloat16* g2   = (__hip_bfloat16*)(wsb + 128450560);       //  29,360,128 (a_v)
    __hip_bfloat16* ob   = g1;                                       //  51,380,224 (o, overlays g1+g2)
    __hip_bfloat16* kb   = (__hip_bfloat16*)(wsb + 157810688);       //  25,690,112
    __hip_bfloat16* vb   = (__hip_bfloat16*)(wsb + 183500800);       //  29,360,128
    float* mu1           = (float*)(wsb + 212860928);
    float* rs1           = mu1 + MTOK;
    short* cidx          = (short*)(wsb + 213663744);
    short* sidx          = (short*)(wsb + 214188032);
    __hip_bfloat16* wkt  = (__hip_bfloat16*)(wsb + 215105536);
    __hip_bfloat16* wvt  = (__hip_bfloat16*)(wsb + 215138304);
    __hip_bfloat16* wpt  = (__hip_bfloat16*)(wsb + 215269376);
    __hip_bfloat16* w1t  = (__hip_bfloat16*)(wsb + 215400448);
    __hip_bfloat16* w2t  = (__hip_bfloat16*)(wsb + 215924736);
    __hip_bfloat16* a2   = (__hip_bfloat16*)qb;                      // overlays dead qb
    __hip_bfloat16* hb   = (__hip_bfloat16*)(wsb + 51380224);        // overlays qb 2nd half
    if (ws_size < 216449024ULL) return;

    // weight transposes (independent, cheap)
    wt_k<<<(128 * 128 + 255) / 256, 256, 0, stream>>>(wk, wkt, 128, 128);
    wt_k<<<(256 * 256 + 255) / 256, 256, 0, stream>>>(wv, wvt, 256, 256);
    wt_k<<<(256 * 256 + 255) / 256, 256, 0, stream>>>(wpj, wpt, 256, 256);
    wt_k<<<(256 * 1024 + 255) / 256, 256, 0, stream>>>(w1, w1t, 256, 1024);
    wt_k<<<(1024 * 256 + 255) / 256, 256, 0, stream>>>(w2, w2t, 1024, 256);

    ln_stats_k<<<MTOK, 64, 0, stream>>>(x, mu1, rs1);

    // q (fp32 — protects top-k index selection)
    GP p{};
    p.W = wq; p.bias = bq; p.C = qb; p.N = CC; p.K = CC;
    p.x = x; p.mu = mu1; p.rs = rs1; p.g = n1g; p.be = n1b;
    gemm_q_k<<<dim3(MTOK / 64, CC / 64), 256, 0, stream>>>(p);

    topk_k<<<NBH, 64, 0, stream>>>(qb, wch, bch, cidx, sidx);

    gather_ch_k<<<MTOK * 128 / 256, 256, 0, stream>>>(qb, cidx, g1);
    MG m{};
    m.A = g1; m.B = wkt; m.bias = bk; m.N = 128; m.K = 128; m.Cb = kb;
    mgemm_k<0><<<dim3(MTOK / 128, 1), 256, 0, stream>>>(m);

    gather_sp_k<<<NWIN * KSP * 256 / 256, 256, 0, stream>>>(qb, sidx, g2);
    m = MG{};
    m.A = g2; m.B = wvt; m.bias = bv; m.N = CC; m.K = CC; m.Cb = vb;
    mgemm_k<0><<<dim3(NWIN * KSP / 128, 2), 256, 0, stream>>>(m);

    attn_k<<<NBH, 64, 0, stream>>>(qb, kb, vb, cidx, sidx, rpb, ob);

    // out = window_reverse(o @ wproj + bproj) + x
    m = MG{};
    m.A = ob; m.B = wpt; m.bias = bpj; m.N = CC; m.K = CC; m.Cf = out; m.resid = x;
    mgemm_k<1><<<dim3(MTOK / 128, 2), 256, 0, stream>>>(m);

    ln2_k<<<MTOK, 64, 0, stream>>>(out, n2g, n2b, a2);

    const int CHUNK = MTOK / 4;
    for (int c = 0; c < 4; ++c) {
        int start = c * CHUNK;
        m = MG{};
        m.A = a2 + (size_t)start * CC; m.B = w1t; m.bias = b1;
        m.N = MLPH; m.K = CC; m.Cb = hb;
        mgemm_k<2><<<dim3(CHUNK / 128, MLPH / 128), 256, 0, stream>>>(m);

        m = MG{};
        m.A = hb; m.B = w2t; m.bias = b2; m.N = CC; m.K = MLPH;
        m.Cf = out; m.resid = out; m.row0 = start;
        mgemm_k<3><<<dim3(CHUNK / 128, CC / 128), 256, 0, stream>>>(m);
    }
}